// Round 9
// baseline (166.637 us; speedup 1.0000x reference)
//
#include <hip/hip_runtime.h>

// B=4, N=2048, C=256, ic=128.  Algebra (validated rounds 1-10 + this round):
//   T=lin(aim,theta) P=lin(detect,phi) Gd=lin(detect,g) Ga=lin(aim,g2)   [bf16]
//   S_aT = Gd_v @ P_v^T ; S_bT = Ga_v @ T_v^T        [128,128] fp32 (atomic accum)
//   out_aim[r,d] = (1/4096)*sum_k S_aT[r/16,k]*TW[16k+(r%16),d] + Wb[d] + aim[r,d]
// Round 11 weight-merge (resubmit — round-8 bench was an infra failure):
//   TW = T@W^T = aim@(W_w@th_w)^T + (W_w@th_b)  => TW = lin(aim, M1, v1),
//   M1/v1 weight-only (computed in prep). Symmetrically PQ = lin(detect, M2, v2).
//   D0 prep (M1,M2,v1,v2 + zero S) -> D1 lin6 (6 uniform linears) ->
//   D2 spart (atomic S) -> D3 combine.  4 dispatches, balanced.

typedef __attribute__((ext_vector_type(4))) float  f32x4;
typedef __attribute__((ext_vector_type(8))) __bf16 bf16x8;
typedef __attribute__((ext_vector_type(8))) unsigned short u16x8;
typedef __attribute__((ext_vector_type(4))) unsigned short u16x4;

__device__ inline unsigned short f2bf(float f) {
    union { float f; unsigned u; } c; c.f = f;
    unsigned r = c.u + 0x7FFF + ((c.u >> 16) & 1);   // RNE
    return (unsigned short)(r >> 16);
}
__device__ inline bf16x8 ldfrag(const unsigned short* p) {
    return __builtin_bit_cast(bf16x8, *(const u16x8*)p);
}

// ---------------- D0: prep — M1/M2, v1/v2, zero S ----------------------------
// grid (34): 0-15 M-GEMM (side=bid>>3; 64x128 tile, K=256, fp32 out);
//            16-17 v matvec; 18-33 zero S.
__global__ __launch_bounds__(256)
void prep_kernel(const float* __restrict__ W_w, const float* __restrict__ Q_w,
                 const float* __restrict__ th_w, const float* __restrict__ ph_w,
                 const float* __restrict__ th_b, const float* __restrict__ ph_b,
                 float* __restrict__ M1, float* __restrict__ M2,
                 float* __restrict__ v1, float* __restrict__ v2,
                 float* __restrict__ S)
{
    __shared__ unsigned short lds[7680];   // GEMM: As[64][40] + Bs[128][40] = 15360 B
    const int bid = blockIdx.x, tid = threadIdx.x;

    if (bid < 16) {
        // M[e,c] = sum_d A[e,d] * Bm[d,c]   (A=W_w or Q_w, Bm=th_w or ph_w)
        const int side = bid >> 3, rem = bid & 7, mtile = rem >> 1, nhalf = rem & 1;
        const float* A  = side ? Q_w : W_w;
        const float* Bm = side ? ph_w : th_w;
        float* Mo = side ? M2 : M1;
        const int m0 = mtile * 64, n0 = nhalf * 128;

        unsigned short (*As)[40] = (unsigned short (*)[40])lds;               // [64][40]
        unsigned short (*Bs)[40] = (unsigned short (*)[40])(lds + 2560);      // [128][40]

        const int lane = tid & 63, w = tid >> 6;
        const int wr = w >> 1, wc = w & 1, q = lane >> 4, ln = lane & 15;

        f32x4 acc[2][4] = {};

        for (int k0 = 0; k0 < 256; k0 += 32) {
            #pragma unroll
            for (int i = 0; i < 2; ++i) {            // A: 64x32 fp32 = 512 float4
                int idx = tid + i * 256, row = idx >> 3, c4 = idx & 7;
                float4 v = *(const float4*)(A + (size_t)(m0 + row) * 256 + k0 + c4 * 4);
                u16x4 p; p[0]=f2bf(v.x); p[1]=f2bf(v.y); p[2]=f2bf(v.z); p[3]=f2bf(v.w);
                *(u16x4*)&As[row][c4 * 4] = p;
            }
            #pragma unroll
            for (int i = 0; i < 4; ++i) {            // B^T: Bm[k0+dr][n0+c] -> Bs[c][dr]
                int idx = tid + i * 256, dr = idx >> 5, c4 = idx & 31;
                float4 v = *(const float4*)(Bm + (size_t)(k0 + dr) * 256 + n0 + c4 * 4);
                Bs[c4 * 4 + 0][dr] = f2bf(v.x); Bs[c4 * 4 + 1][dr] = f2bf(v.y);
                Bs[c4 * 4 + 2][dr] = f2bf(v.z); Bs[c4 * 4 + 3][dr] = f2bf(v.w);
            }
            __syncthreads();
            bf16x8 af[2], bb[4];
            #pragma unroll
            for (int i = 0; i < 2; ++i) af[i] = ldfrag(&As[wr * 32 + i * 16 + ln][q * 8]);
            #pragma unroll
            for (int j = 0; j < 4; ++j) bb[j] = ldfrag(&Bs[wc * 64 + j * 16 + ln][q * 8]);
            #pragma unroll
            for (int i = 0; i < 2; ++i)
                #pragma unroll
                for (int j = 0; j < 4; ++j)
                    acc[i][j] = __builtin_amdgcn_mfma_f32_16x16x32_bf16(af[i], bb[j], acc[i][j], 0, 0, 0);
            __syncthreads();
        }

        #pragma unroll
        for (int i = 0; i < 2; ++i)
            #pragma unroll
            for (int j = 0; j < 4; ++j) {
                int n = n0 + wc * 64 + j * 16 + ln;
                #pragma unroll
                for (int r = 0; r < 4; ++r) {
                    int m = m0 + wr * 32 + i * 16 + q * 4 + r;
                    Mo[(size_t)m * 256 + n] = acc[i][j][r];      // fp32, no bias
                }
            }
    } else if (bid < 18) {
        // v[e] = sum_d Wsrc[e,d] * bsrc[d]
        const int side = bid - 16;
        const float* Wsrc = side ? Q_w : W_w;
        const float* bsrc = side ? ph_b : th_b;
        float* vout = side ? v2 : v1;
        float* bs = (float*)lds;                     // 256 floats
        if (tid < 64) *(float4*)(bs + tid * 4) = *(const float4*)(bsrc + tid * 4);
        __syncthreads();
        const int g = tid >> 2, sub = tid & 3;       // 4 lanes per e, lane-adjacent
        #pragma unroll
        for (int p = 0; p < 4; ++p) {
            int e = p * 64 + g;
            float s = 0.f;
            #pragma unroll
            for (int jj = 0; jj < 16; ++jj) {
                float4 v = *(const float4*)(Wsrc + (size_t)e * 256 + sub * 64 + jj * 4);
                int b0 = sub * 64 + jj * 4;
                s += v.x * bs[b0] + v.y * bs[b0 + 1] + v.z * bs[b0 + 2] + v.w * bs[b0 + 3];
            }
            s += __shfl_xor(s, 1); s += __shfl_xor(s, 2);
            if (sub == 0) vout[e] = s;
        }
    } else {
        // zero S: 131072 floats over 16 blocks
        const int b = bid - 18;
        float4 z = {0.f, 0.f, 0.f, 0.f};
        #pragma unroll
        for (int i = 0; i < 8; ++i)
            ((float4*)S)[(size_t)b * 2048 + tid + i * 256] = z;
    }
}

// ---------------- D1: six input linears (fp32 in, inline convert) ------------
// grid (768): mat = bid>>7 (0:T 1:Ga 2:TW 3:P 4:Gd 5:PQ), mtile = bid&127.
// Tile 64x256, BK=32.  (body = round-10 lin4, verified)
__global__ __launch_bounds__(256)
void lin6_kernel(const float* __restrict__ aim, const float* __restrict__ detect,
                 const float* __restrict__ th_w, const float* __restrict__ g2_w,
                 const float* __restrict__ ph_w, const float* __restrict__ g_w,
                 const float* __restrict__ th_b, const float* __restrict__ g2_b,
                 const float* __restrict__ ph_b, const float* __restrict__ g_b,
                 const float* __restrict__ M1, const float* __restrict__ M2,
                 const float* __restrict__ v1, const float* __restrict__ v2,
                 unsigned short* __restrict__ T,  unsigned short* __restrict__ Ga,
                 unsigned short* __restrict__ TW, unsigned short* __restrict__ P,
                 unsigned short* __restrict__ Gd, unsigned short* __restrict__ PQ)
{
    const int bid = blockIdx.x, tid = threadIdx.x;
    const int lane = tid & 63, w = tid >> 6;
    const int wr = w >> 1, wc = w & 1, q = lane >> 4, ln = lane & 15;

    const int mat = bid >> 7, mtile = bid & 127;
    const float* Ap; const float* Wm; const float* Bv; unsigned short* O;
    switch (mat) {
        case 0:  Ap = aim;    Wm = th_w; Bv = th_b; O = T;  break;
        case 1:  Ap = aim;    Wm = g2_w; Bv = g2_b; O = Ga; break;
        case 2:  Ap = aim;    Wm = M1;   Bv = v1;   O = TW; break;
        case 3:  Ap = detect; Wm = ph_w; Bv = ph_b; O = P;  break;
        case 4:  Ap = detect; Wm = g_w;  Bv = g_b;  O = Gd; break;
        default: Ap = detect; Wm = M2;   Bv = v2;   O = PQ; break;
    }
    const int m0 = mtile * 64;

    __shared__ unsigned short As[64][40];    // [m][k] bf16
    __shared__ unsigned short Bs[256][40];   // [n][k]

    f32x4 acc[2][8] = {};

    for (int k0 = 0; k0 < 256; k0 += 32) {
        #pragma unroll
        for (int i = 0; i < 2; ++i) {            // A: 64x32 fp32 = 512 float4
            int idx = tid + i * 256, row = idx >> 3, c4 = idx & 7;
            float4 v = *(const float4*)(Ap + (size_t)(m0 + row) * 256 + k0 + c4 * 4);
            u16x4 p; p[0]=f2bf(v.x); p[1]=f2bf(v.y); p[2]=f2bf(v.z); p[3]=f2bf(v.w);
            *(u16x4*)&As[row][c4 * 4] = p;
        }
        #pragma unroll
        for (int i = 0; i < 8; ++i) {            // W: 256x32 fp32 = 2048 float4
            int idx = tid + i * 256, row = idx >> 3, c4 = idx & 7;
            float4 v = *(const float4*)(Wm + (size_t)row * 256 + k0 + c4 * 4);
            u16x4 p; p[0]=f2bf(v.x); p[1]=f2bf(v.y); p[2]=f2bf(v.z); p[3]=f2bf(v.w);
            *(u16x4*)&Bs[row][c4 * 4] = p;
        }
        __syncthreads();
        bf16x8 af[2], bb[8];
        #pragma unroll
        for (int i = 0; i < 2; ++i) af[i] = ldfrag(&As[wr * 32 + i * 16 + ln][q * 8]);
        #pragma unroll
        for (int j = 0; j < 8; ++j) bb[j] = ldfrag(&Bs[wc * 128 + j * 16 + ln][q * 8]);
        #pragma unroll
        for (int i = 0; i < 2; ++i)
            #pragma unroll
            for (int j = 0; j < 8; ++j)
                acc[i][j] = __builtin_amdgcn_mfma_f32_16x16x32_bf16(af[i], bb[j], acc[i][j], 0, 0, 0);
        __syncthreads();
    }

    #pragma unroll
    for (int i = 0; i < 2; ++i)
        #pragma unroll
        for (int j = 0; j < 8; ++j) {
            int n = wc * 128 + j * 16 + ln;
            float bias = Bv[n];
            #pragma unroll
            for (int r = 0; r < 4; ++r) {
                int m = m0 + wr * 32 + i * 16 + q * 4 + r;
                O[(size_t)m * 256 + n] = f2bf(acc[i][j][r] + bias);
            }
        }
}

// ---------------- D2: S partials 64x64, KC=256, atomic into S ---------------
// grid (512): which=bid>>8, batch=(bid>>6)&3, mt, nt, chunk(16).
// (= round-10 mid s_part branch, verified)
__global__ __launch_bounds__(256)
void spart_kernel(const unsigned short* __restrict__ T, const unsigned short* __restrict__ P,
                  const unsigned short* __restrict__ Gd, const unsigned short* __restrict__ Ga,
                  float* __restrict__ S)
{
    const int bid = blockIdx.x, tid = threadIdx.x;
    const int lane = tid & 63, w = tid >> 6;
    const int wr = w >> 1, wc = w & 1, q = lane >> 4, ln = lane & 15;

    const int which = bid >> 8, rem = bid & 255, batch = rem >> 6, rem2 = rem & 63;
    const int mt = rem2 >> 5, nt = (rem2 >> 4) & 1, chunk = rem2 & 15;
    const unsigned short* Ap = (which ? Ga : Gd) + (size_t)batch * 524288;
    const unsigned short* Bp = (which ? T  : P ) + (size_t)batch * 524288;
    float* Sp = S + ((size_t)(which * 4 + batch) << 14);
    const int kbeg = chunk * 256, m0 = mt * 64, n0 = nt * 64;

    __shared__ unsigned short As[64][72];
    __shared__ unsigned short Bs[64][72];

    f32x4 acc[2][2] = {};

    for (int kk = 0; kk < 4; ++kk) {
        const int k0 = kbeg + kk * 64;
        #pragma unroll
        for (int i = 0; i < 2; ++i) {            // A,B: 64x64 bf16 = 512 u16x8 each
            int c = tid + i * 256, row = c >> 3, c8 = c & 7;
            *(u16x8*)&As[row][c8 * 8] = *(const u16x8*)(Ap + (size_t)(m0 + row) * 4096 + k0 + c8 * 8);
            *(u16x8*)&Bs[row][c8 * 8] = *(const u16x8*)(Bp + (size_t)(n0 + row) * 4096 + k0 + c8 * 8);
        }
        __syncthreads();
        #pragma unroll
        for (int ks = 0; ks < 2; ++ks) {
            bf16x8 af[2], bb[2];
            #pragma unroll
            for (int i = 0; i < 2; ++i) af[i] = ldfrag(&As[wr * 32 + i * 16 + ln][ks * 32 + q * 8]);
            #pragma unroll
            for (int j = 0; j < 2; ++j) bb[j] = ldfrag(&Bs[wc * 32 + j * 16 + ln][ks * 32 + q * 8]);
            #pragma unroll
            for (int i = 0; i < 2; ++i)
                #pragma unroll
                for (int j = 0; j < 2; ++j)
                    acc[i][j] = __builtin_amdgcn_mfma_f32_16x16x32_bf16(af[i], bb[j], acc[i][j], 0, 0, 0);
        }
        __syncthreads();
    }

    #pragma unroll
    for (int i = 0; i < 2; ++i)
        #pragma unroll
        for (int j = 0; j < 2; ++j)
            #pragma unroll
            for (int r = 0; r < 4; ++r) {
                int m = m0 + wr * 32 + i * 16 + q * 4 + r, n = n0 + wc * 32 + j * 16 + ln;
                unsafeAtomicAdd(Sp + m * 128 + n, acc[i][j][r]);   // HW global_atomic_add_f32
            }
}

// ---------------- D3: combine  out = S~ @ TW_q + bias + residual -------------
// grid (512). (= round-10 combine, verified)
__global__ __launch_bounds__(256)
void combine_kernel(const float* __restrict__ S,
                    const unsigned short* __restrict__ TW, const unsigned short* __restrict__ PQ,
                    const float* __restrict__ W_b, const float* __restrict__ Q_b,
                    const float* __restrict__ aim, const float* __restrict__ detect,
                    float* __restrict__ out_aim, float* __restrict__ out_det)
{
    const int bid = blockIdx.x, tid = threadIdx.x;
    const int lane = tid & 63, w = tid >> 6;
    const int wr = w >> 1, wc = w & 1, q = lane >> 4, ln = lane & 15;

    const int which = bid >> 8, batch = (bid >> 6) & 3, qq = (bid >> 2) & 15;
    const int dtile = (bid >> 1) & 1, ihalf = bid & 1;
    const int d0 = dtile * 128, i0 = ihalf * 64;
    const float* Sm = S + ((size_t)(which * 4 + batch) << 14);
    const unsigned short* Bsrc = (which ? PQ : TW) + (size_t)batch * 524288;
    const float* Bv = which ? Q_b : W_b;
    const float* R  = (which ? detect : aim) + (size_t)batch * 524288;
    float* O = (which ? out_det : out_aim) + (size_t)batch * 524288;

    __shared__ unsigned short As[64][72];    // S~ [i][k] bf16 (scaled)
    __shared__ unsigned short Bs[128][72];   // TW_q^T [d][k]

    f32x4 acc[2][4] = {};

    for (int kk = 0; kk < 2; ++kk) {
        const int k0 = kk * 64;
        #pragma unroll
        for (int i = 0; i < 4; ++i) {            // A: 64x64 fp32, scale+convert
            int idx = tid + i * 256, row = idx >> 4, c4 = idx & 15;
            float4 v = *(const float4*)(Sm + (size_t)(i0 + row) * 128 + k0 + c4 * 4);
            u16x4 p;
            p[0]=f2bf(v.x * (1.0f/4096.0f)); p[1]=f2bf(v.y * (1.0f/4096.0f));
            p[2]=f2bf(v.z * (1.0f/4096.0f)); p[3]=f2bf(v.w * (1.0f/4096.0f));
            *(u16x4*)&As[row][c4 * 4] = p;
        }
        #pragma unroll
        for (int i = 0; i < 4; ++i) {            // B: gather 64 rows 16k+qq, transpose
            int c = tid + i * 256, krow = c >> 4, dc = (c & 15) * 8;
            int gr = 16 * (k0 + krow) + qq;
            u16x8 v = *(const u16x8*)(Bsrc + (size_t)gr * 256 + d0 + dc);
            #pragma unroll
            for (int jj = 0; jj < 8; ++jj) Bs[dc + jj][krow] = v[jj];
        }
        __syncthreads();
        #pragma unroll
        for (int ks = 0; ks < 2; ++ks) {
            bf16x8 af[2], bb[4];
            #pragma unroll
            for (int i = 0; i < 2; ++i) af[i] = ldfrag(&As[wr * 32 + i * 16 + ln][ks * 32 + q * 8]);
            #pragma unroll
            for (int j = 0; j < 4; ++j) bb[j] = ldfrag(&Bs[wc * 64 + j * 16 + ln][ks * 32 + q * 8]);
            #pragma unroll
            for (int i = 0; i < 2; ++i)
                #pragma unroll
                for (int j = 0; j < 4; ++j)
                    acc[i][j] = __builtin_amdgcn_mfma_f32_16x16x32_bf16(af[i], bb[j], acc[i][j], 0, 0, 0);
        }
        __syncthreads();
    }

    #pragma unroll
    for (int i = 0; i < 2; ++i)
        #pragma unroll
        for (int j = 0; j < 4; ++j) {
            int d = d0 + wc * 64 + j * 16 + ln;
            float bias = Bv[d];
            #pragma unroll
            for (int r = 0; r < 4; ++r) {
                int iS = i0 + wr * 32 + i * 16 + q * 4 + r;
                size_t off = (size_t)(16 * iS + qq) * 256 + d;
                O[off] = acc[i][j][r] + bias + R[off];
            }
        }
}

extern "C" void kernel_launch(void* const* d_in, const int* in_sizes, int n_in,
                              void* d_out, int out_size, void* d_ws, size_t ws_size,
                              hipStream_t stream)
{
    const float* detect = (const float*)d_in[0];
    const float* aim    = (const float*)d_in[1];
    const float* g_w  = (const float*)d_in[2];  const float* g_b  = (const float*)d_in[3];
    const float* g2_w = (const float*)d_in[4];  const float* g2_b = (const float*)d_in[5];
    const float* th_w = (const float*)d_in[6];  const float* th_b = (const float*)d_in[7];
    const float* ph_w = (const float*)d_in[8];  const float* ph_b = (const float*)d_in[9];
    const float* W_w  = (const float*)d_in[10]; const float* W_b  = (const float*)d_in[11];
    const float* Q_w  = (const float*)d_in[12]; const float* Q_b  = (const float*)d_in[13];

    const size_t TOT = 8192L * 256;   // 2,097,152 elems per tensor

    unsigned short* ws16 = (unsigned short*)d_ws;
    unsigned short* T   = ws16;
    unsigned short* P   = T  + TOT;
    unsigned short* Gd  = P  + TOT;
    unsigned short* Ga  = Gd + TOT;
    unsigned short* TW  = Ga + TOT;             // lin(aim, M1, v1)  bf16 [8192,256]
    unsigned short* PQ  = TW + TOT;             // lin(det, M2, v2)  bf16 [8192,256]
    float* S    = (float*)(PQ + TOT);           // [2][4][128][128] fp32 (atomic accum)
    float* M1   = S + 131072;                   // [256,256] fp32 = W_w @ th_w
    float* M2   = M1 + 65536;                   // [256,256] fp32 = Q_w @ ph_w
    float* v1   = M2 + 65536;                   // [256] fp32 = W_w @ th_b
    float* v2   = v1 + 256;                     // [256] fp32 = Q_w @ ph_b

    float* out_det = (float*)d_out;
    float* out_aim = out_det + TOT;

    prep_kernel<<<dim3(34), 256, 0, stream>>>(
        W_w, Q_w, th_w, ph_w, th_b, ph_b, M1, M2, v1, v2, S);
    lin6_kernel<<<dim3(768), 256, 0, stream>>>(
        aim, detect, th_w, g2_w, ph_w, g_w, th_b, g2_b, ph_b, g_b,
        M1, M2, v1, v2, T, Ga, TW, P, Gd, PQ);
    spart_kernel<<<dim3(512), 256, 0, stream>>>(T, P, Gd, Ga, S);
    combine_kernel<<<dim3(512), 256, 0, stream>>>(
        S, TW, PQ, W_b, Q_b, aim, detect, out_aim, out_det);
}